// Round 1
// baseline (36.351 us; speedup 1.0000x reference)
//
#include <hip/hip_runtime.h>

#define NUM_CLASSES 4096
#define ROWS 8192

// One block per row. Each thread processes 16 contiguous-ish floats via 4x float4
// strided loads, maintaining an online-softmax triple (m, s, w):
//   m = running max, s = sum exp(x-m), w = sum exp(x-m)*|class - target|
// Then wave shfl_xor reduction + cross-wave LDS merge.
__global__ __launch_bounds__(256) void w1_row_kernel(const float* __restrict__ logits,
                                                     const int* __restrict__ targets,
                                                     float* __restrict__ row_w1) {
    const int r = blockIdx.x;
    const int tid = threadIdx.x;
    const float t = (float)targets[r];
    const float4* rowp = reinterpret_cast<const float4*>(logits + (size_t)r * NUM_CLASSES);

    float m = -3.0e38f, s = 0.0f, w = 0.0f;
    #pragma unroll
    for (int k = 0; k < 4; ++k) {
        const int vecIdx = k * 256 + tid;          // float4 index within row
        const float4 v = rowp[vecIdx];
        const int j0 = vecIdx * 4;
        const float xs[4] = {v.x, v.y, v.z, v.w};
        #pragma unroll
        for (int e = 0; e < 4; ++e) {
            const float x = xs[e];
            const float d = fabsf((float)(j0 + e) - t);
            if (x > m) {
                const float c = __expf(m - x);
                s *= c; w *= c; m = x;
            }
            const float ex = __expf(x - m);
            s += ex;
            w += ex * d;
        }
    }

    // 64-lane butterfly reduction, merging online-softmax states
    #pragma unroll
    for (int off = 1; off < 64; off <<= 1) {
        const float m2 = __shfl_xor(m, off, 64);
        const float s2 = __shfl_xor(s, off, 64);
        const float w2 = __shfl_xor(w, off, 64);
        const float mm = fmaxf(m, m2);
        const float c1 = __expf(m - mm);
        const float c2 = __expf(m2 - mm);
        s = s * c1 + s2 * c2;
        w = w * c1 + w2 * c2;
        m = mm;
    }

    __shared__ float sm[4], ss[4], sw[4];
    const int wave = tid >> 6;
    if ((tid & 63) == 0) { sm[wave] = m; ss[wave] = s; sw[wave] = w; }
    __syncthreads();

    if (tid == 0) {
        m = sm[0]; s = ss[0]; w = sw[0];
        #pragma unroll
        for (int i = 1; i < 4; ++i) {
            const float mm = fmaxf(m, sm[i]);
            const float c1 = __expf(m - mm);
            const float c2 = __expf(sm[i] - mm);
            s = s * c1 + ss[i] * c2;
            w = w * c1 + sw[i] * c2;
            m = mm;
        }
        row_w1[r] = (w / s) * (1.0f / NUM_CLASSES);
    }
}

// Deterministic final reduction: one block sums all 8192 per-row values.
__global__ __launch_bounds__(256) void w1_reduce_kernel(const float* __restrict__ row_w1,
                                                        float* __restrict__ out) {
    const int tid = threadIdx.x;
    float acc = 0.0f;
    for (int i = tid; i < ROWS; i += 256) acc += row_w1[i];

    #pragma unroll
    for (int off = 1; off < 64; off <<= 1) acc += __shfl_xor(acc, off, 64);

    __shared__ float sa[4];
    if ((tid & 63) == 0) sa[tid >> 6] = acc;
    __syncthreads();

    if (tid == 0) {
        out[0] = (sa[0] + sa[1] + sa[2] + sa[3]) * (1.0f / ROWS);
    }
}

extern "C" void kernel_launch(void* const* d_in, const int* in_sizes, int n_in,
                              void* d_out, int out_size, void* d_ws, size_t ws_size,
                              hipStream_t stream) {
    const float* logits = (const float*)d_in[0];
    const int* targets = (const int*)d_in[1];
    float* out = (float*)d_out;
    float* row_w1 = (float*)d_ws;   // 8192 floats = 32 KB scratch

    w1_row_kernel<<<ROWS, 256, 0, stream>>>(logits, targets, row_w1);
    w1_reduce_kernel<<<1, 256, 0, stream>>>(row_w1, out);
}

// Round 4
// 27.464 us; speedup vs baseline: 1.3236x; 1.3236x over previous
//
#include <hip/hip_runtime.h>

#define NUM_CLASSES 4096
#define ROWS 8192

// One block (256 threads = 4 waves) per row.
// Phase 1: block-wide row max (register fmax tree + shfl + LDS).
// Phase 2: 16 independent exp(x - m) per thread, accumulate
//   s = sum(exp), w = sum(exp * |class - target|), then plain-add reduce.
// W1-vs-delta identity: sum_c |cdf[c] - 1[c>=t]| = sum_j p[j]*|j - t|.
__global__ __launch_bounds__(256) void w1_row_kernel(const float* __restrict__ logits,
                                                     const int* __restrict__ targets,
                                                     float* __restrict__ row_w1) {
    const int r = blockIdx.x;
    const int tid = threadIdx.x;
    const float4* rowp = reinterpret_cast<const float4*>(logits + (size_t)r * NUM_CLASSES);

    // Issue all four 16B loads up front (64 B/lane, fully coalesced).
    const float4 v0 = rowp[tid];
    const float4 v1 = rowp[256 + tid];
    const float4 v2 = rowp[512 + tid];
    const float4 v3 = rowp[768 + tid];
    const float t = (float)targets[r];

    // ---- Phase 1: block-wide max ----
    float m = fmaxf(fmaxf(fmaxf(v0.x, v0.y), fmaxf(v0.z, v0.w)),
                    fmaxf(fmaxf(v1.x, v1.y), fmaxf(v1.z, v1.w)));
    m = fmaxf(m, fmaxf(fmaxf(fmaxf(v2.x, v2.y), fmaxf(v2.z, v2.w)),
                       fmaxf(fmaxf(v3.x, v3.y), fmaxf(v3.z, v3.w))));
    #pragma unroll
    for (int off = 1; off < 64; off <<= 1) m = fmaxf(m, __shfl_xor(m, off, 64));

    __shared__ float smax[4];
    __shared__ float ssum[4];
    __shared__ float swsum[4];
    const int wave = tid >> 6;
    if ((tid & 63) == 0) smax[wave] = m;
    __syncthreads();
    m = fmaxf(fmaxf(smax[0], smax[1]), fmaxf(smax[2], smax[3]));

    // ---- Phase 2: independent exps; split accumulators for ILP ----
    // element index: j = chunk*1024 + tid*4 + e  ->  d = |c + (chunk*1024 + e)|
    const float c = (float)(tid * 4) - t;
    float s0 = 0.f, s1 = 0.f, w0 = 0.f, w1 = 0.f;

#define W1_ACC(vv, base, S, W)                                              \
    {                                                                       \
        const float e0 = __expf(vv.x - m);                                  \
        const float e1 = __expf(vv.y - m);                                  \
        const float e2 = __expf(vv.z - m);                                  \
        const float e3 = __expf(vv.w - m);                                  \
        S += (e0 + e1) + (e2 + e3);                                         \
        W += e0 * fabsf(c + (base + 0.f)) + e1 * fabsf(c + (base + 1.f))   \
           + e2 * fabsf(c + (base + 2.f)) + e3 * fabsf(c + (base + 3.f)); \
    }

    W1_ACC(v0, 0.f, s0, w0)
    W1_ACC(v1, 1024.f, s1, w1)
    W1_ACC(v2, 2048.f, s0, w0)
    W1_ACC(v3, 3072.f, s1, w1)
#undef W1_ACC

    float s = s0 + s1;
    float w = w0 + w1;

    // ---- plain-add block reduction (no rescale needed: shared m) ----
    #pragma unroll
    for (int off = 1; off < 64; off <<= 1) {
        s += __shfl_xor(s, off, 64);
        w += __shfl_xor(w, off, 64);
    }
    if ((tid & 63) == 0) { ssum[wave] = s; swsum[wave] = w; }
    __syncthreads();

    if (tid == 0) {
        s = (ssum[0] + ssum[1]) + (ssum[2] + ssum[3]);
        w = (swsum[0] + swsum[1]) + (swsum[2] + swsum[3]);
        row_w1[r] = (w / s) * (1.0f / NUM_CLASSES);
    }
}

// Deterministic final reduction: one block sums all 8192 per-row values.
__global__ __launch_bounds__(256) void w1_reduce_kernel(const float* __restrict__ row_w1,
                                                        float* __restrict__ out) {
    const int tid = threadIdx.x;
    const float4* p = reinterpret_cast<const float4*>(row_w1);
    float acc = 0.0f;
    // 8192 floats = 2048 float4; 256 threads x 8 float4 each
    #pragma unroll
    for (int k = 0; k < 8; ++k) {
        const float4 v = p[k * 256 + tid];
        acc += (v.x + v.y) + (v.z + v.w);
    }

    #pragma unroll
    for (int off = 1; off < 64; off <<= 1) acc += __shfl_xor(acc, off, 64);

    __shared__ float sa[4];
    if ((tid & 63) == 0) sa[tid >> 6] = acc;
    __syncthreads();

    if (tid == 0) {
        out[0] = ((sa[0] + sa[1]) + (sa[2] + sa[3])) * (1.0f / ROWS);
    }
}

extern "C" void kernel_launch(void* const* d_in, const int* in_sizes, int n_in,
                              void* d_out, int out_size, void* d_ws, size_t ws_size,
                              hipStream_t stream) {
    const float* logits = (const float*)d_in[0];
    const int* targets = (const int*)d_in[1];
    float* out = (float*)d_out;
    float* row_w1 = (float*)d_ws;   // 8192 floats = 32 KB scratch

    w1_row_kernel<<<ROWS, 256, 0, stream>>>(logits, targets, row_w1);
    w1_reduce_kernel<<<1, 256, 0, stream>>>(row_w1, out);
}